// Round 1
// baseline (150.615 us; speedup 1.0000x reference)
//
#include <hip/hip_runtime.h>

typedef __attribute__((ext_vector_type(8))) short bf16x8;
typedef __attribute__((ext_vector_type(4))) float f32x4;

#define D_MODEL 1024
#define SEQ 1024
#define NB 4
#define NH 16
#define DH 64
#define BHCOUNT 64
#define MROWS 4096

__device__ __forceinline__ unsigned short f2bf(float f) {
    union { float f; unsigned u; } x; x.f = f;
    unsigned r = x.u + 0x7fffu + ((x.u >> 16) & 1u);
    return (unsigned short)(r >> 16);
}

__device__ __forceinline__ void gload16(const void* g, void* l) {
    __builtin_amdgcn_global_load_lds((const __attribute__((address_space(1))) void*)g,
                                     (__attribute__((address_space(3))) void*)l, 16, 0, 0);
}

// ---------------- convert inp f32 -> bf16 ----------------
__global__ __launch_bounds__(256) void cvt_x(const float* __restrict__ x,
                                             unsigned short* __restrict__ o) {
    int i = blockIdx.x * 256 + threadIdx.x;   // each handles 4 floats
    float4 v = ((const float4*)x)[i];
    ushort4 r;
    r.x = f2bf(v.x); r.y = f2bf(v.y); r.z = f2bf(v.z); r.w = f2bf(v.w);
    ((ushort4*)o)[i] = r;
}

// ---------------- transpose W (f32) -> bf16 W^T ----------------
__global__ __launch_bounds__(256) void transpose_w(const float* __restrict__ Wq,
                                                   const float* __restrict__ Wk,
                                                   const float* __restrict__ Wv,
                                                   const float* __restrict__ Wo,
                                                   unsigned short* __restrict__ Wqkv_t,
                                                   unsigned short* __restrict__ Wo_t) {
    __shared__ float tile[32][33];
    const int mtx = blockIdx.z;
    const float* src = mtx == 0 ? Wq : mtx == 1 ? Wk : mtx == 2 ? Wv : Wo;
    unsigned short* dst = mtx < 3 ? (Wqkv_t + (size_t)mtx * D_MODEL * D_MODEL) : Wo_t;
    const int n0 = blockIdx.x * 32, k0 = blockIdx.y * 32;
    const int tx = threadIdx.x, ty = threadIdx.y;
    #pragma unroll
    for (int i = 0; i < 32; i += 8)
        tile[ty + i][tx] = src[(size_t)(k0 + ty + i) * D_MODEL + n0 + tx];
    __syncthreads();
    #pragma unroll
    for (int i = 0; i < 32; i += 8)
        dst[(size_t)(n0 + ty + i) * D_MODEL + k0 + tx] = f2bf(tile[tx][ty + i]);
}

// ---------------- QKV GEMM: Xb[4096][1024] @ Wqkv_t^T -> Q,K,V bf16 [bh][s][64] ----------------
__global__ __launch_bounds__(256) void gemm_qkv(const unsigned short* __restrict__ Xb,
                                                const unsigned short* __restrict__ Wt,
                                                const float* __restrict__ bq,
                                                const float* __restrict__ bk,
                                                const float* __restrict__ bv,
                                                unsigned short* __restrict__ Qb,
                                                unsigned short* __restrict__ Kb,
                                                unsigned short* __restrict__ Vb) {
    __shared__ unsigned short As[128 * 32];
    __shared__ unsigned short Bs[128 * 32];
    const int tid = threadIdx.x;
    const int lane = tid & 63, wid = tid >> 6;
    const int fr = lane & 15, fg = lane >> 4;
    const int wr = wid >> 1, wc = wid & 1;
    const int m0 = blockIdx.x * 128, n0 = blockIdx.y * 128;
    const unsigned short* Ag = Xb + (size_t)m0 * D_MODEL;
    const unsigned short* Bg = Wt + (size_t)n0 * D_MODEL;
    f32x4 acc[4][4] = {};
    for (int kt = 0; kt < D_MODEL; kt += 32) {
        __syncthreads();
        #pragma unroll
        for (int r = 0; r < 2; ++r) {
            int chunk = r * 256 + tid;
            int row = chunk >> 2, col = (chunk & 3) * 8;
            gload16(Ag + (size_t)row * D_MODEL + kt + col, &As[row * 32 + col]);
            gload16(Bg + (size_t)row * D_MODEL + kt + col, &Bs[row * 32 + col]);
        }
        __syncthreads();
        bf16x8 af[4], bfv[4];
        #pragma unroll
        for (int m = 0; m < 4; ++m) af[m] = *(const bf16x8*)&As[(wr * 64 + m * 16 + fr) * 32 + fg * 8];
        #pragma unroll
        for (int n = 0; n < 4; ++n) bfv[n] = *(const bf16x8*)&Bs[(wc * 64 + n * 16 + fr) * 32 + fg * 8];
        #pragma unroll
        for (int m = 0; m < 4; ++m)
            #pragma unroll
            for (int n = 0; n < 4; ++n)
                acc[m][n] = __builtin_amdgcn_mfma_f32_16x16x32_bf16(af[m], bfv[n], acc[m][n], 0, 0, 0);
    }
    #pragma unroll
    for (int n = 0; n < 4; ++n) {
        int gn = n0 + wc * 64 + n * 16 + fr;
        int sel = gn >> 10, np = gn & 1023;
        const float* bp = sel == 0 ? bq : sel == 1 ? bk : bv;
        unsigned short* dst = sel == 0 ? Qb : sel == 1 ? Kb : Vb;
        float bias = bp[np];
        int h = np >> 6, d = np & 63;
        #pragma unroll
        for (int m = 0; m < 4; ++m) {
            #pragma unroll
            for (int r = 0; r < 4; ++r) {
                int gm = m0 + wr * 64 + m * 16 + fg * 4 + r;
                int b = gm >> 10, s = gm & 1023;
                int bh = b * NH + h;
                dst[((size_t)bh * SEQ + s) * DH + d] = f2bf(acc[m][n][r] + bias);
            }
        }
    }
}

// ---------------- O-proj GEMM: AF bf16 [4096][1024] @ Wo_t^T -> tmp f32 ----------------
__global__ __launch_bounds__(256) void gemm_o(const unsigned short* __restrict__ Ab,
                                              const unsigned short* __restrict__ Wt,
                                              float* __restrict__ tmp) {
    __shared__ unsigned short As[128 * 32];
    __shared__ unsigned short Bs[128 * 32];
    const int tid = threadIdx.x;
    const int lane = tid & 63, wid = tid >> 6;
    const int fr = lane & 15, fg = lane >> 4;
    const int wr = wid >> 1, wc = wid & 1;
    const int m0 = blockIdx.x * 128, n0 = blockIdx.y * 128;
    const unsigned short* Ag = Ab + (size_t)m0 * D_MODEL;
    const unsigned short* Bg = Wt + (size_t)n0 * D_MODEL;
    f32x4 acc[4][4] = {};
    for (int kt = 0; kt < D_MODEL; kt += 32) {
        __syncthreads();
        #pragma unroll
        for (int r = 0; r < 2; ++r) {
            int chunk = r * 256 + tid;
            int row = chunk >> 2, col = (chunk & 3) * 8;
            gload16(Ag + (size_t)row * D_MODEL + kt + col, &As[row * 32 + col]);
            gload16(Bg + (size_t)row * D_MODEL + kt + col, &Bs[row * 32 + col]);
        }
        __syncthreads();
        bf16x8 af[4], bfv[4];
        #pragma unroll
        for (int m = 0; m < 4; ++m) af[m] = *(const bf16x8*)&As[(wr * 64 + m * 16 + fr) * 32 + fg * 8];
        #pragma unroll
        for (int n = 0; n < 4; ++n) bfv[n] = *(const bf16x8*)&Bs[(wc * 64 + n * 16 + fr) * 32 + fg * 8];
        #pragma unroll
        for (int m = 0; m < 4; ++m)
            #pragma unroll
            for (int n = 0; n < 4; ++n)
                acc[m][n] = __builtin_amdgcn_mfma_f32_16x16x32_bf16(af[m], bfv[n], acc[m][n], 0, 0, 0);
    }
    #pragma unroll
    for (int n = 0; n < 4; ++n) {
        int gn = n0 + wc * 64 + n * 16 + fr;
        #pragma unroll
        for (int m = 0; m < 4; ++m) {
            #pragma unroll
            for (int r = 0; r < 4; ++r) {
                int gm = m0 + wr * 64 + m * 16 + fg * 4 + r;
                tmp[(size_t)gm * D_MODEL + gn] = acc[m][n][r];
            }
        }
    }
}

// ---------------- flash attention ----------------
__global__ __launch_bounds__(256) void attn_kernel(const unsigned short* __restrict__ Qb,
                                                   const unsigned short* __restrict__ Kb,
                                                   const unsigned short* __restrict__ Vb,
                                                   const int* __restrict__ amask,
                                                   unsigned short* __restrict__ AF) {
    __shared__ unsigned short Ks[64 * 72];
    __shared__ unsigned short Vts[64 * 72];
    __shared__ unsigned short Ps[4][32 * 72];
    const int tid = threadIdx.x, lane = tid & 63, wid = tid >> 6;
    const int fr = lane & 15, fg = lane >> 4;
    const int bh = blockIdx.y, qt = blockIdx.x;
    const int b = bh >> 4;
    const unsigned short* Qh = Qb + (size_t)bh * SEQ * DH;
    const unsigned short* Kh = Kb + (size_t)bh * SEQ * DH;
    const unsigned short* Vh = Vb + (size_t)bh * SEQ * DH;
    const int q0 = qt * 128 + wid * 32;
    bf16x8 qf[2][2];
    #pragma unroll
    for (int m = 0; m < 2; ++m)
        #pragma unroll
        for (int c = 0; c < 2; ++c)
            qf[m][c] = *(const bf16x8*)(Qh + (size_t)(q0 + m * 16 + fr) * DH + c * 32 + fg * 8);
    f32x4 oacc[2][4] = {};
    float mrun[2][4], lrun[2][4];
    #pragma unroll
    for (int m = 0; m < 2; ++m)
        #pragma unroll
        for (int r = 0; r < 4; ++r) { mrun[m][r] = -3.0e38f; lrun[m][r] = 0.f; }

    for (int kt = 0; kt < 16; ++kt) {
        const int kv0 = kt * 64;
        __syncthreads();
        #pragma unroll
        for (int c2 = 0; c2 < 2; ++c2) {
            int chunk = tid * 2 + c2;
            int row = chunk >> 3, col = (chunk & 7) * 8;
            int4 kd = *(const int4*)(Kh + (size_t)(kv0 + row) * DH + col);
            *(int4*)&Ks[row * 72 + col] = kd;
            int4 vd = *(const int4*)(Vh + (size_t)(kv0 + row) * DH + col);
            union { int4 v; unsigned short u[8]; } uu; uu.v = vd;
            #pragma unroll
            for (int j = 0; j < 8; ++j) Vts[(col + j) * 72 + row] = uu.u[j];
        }
        __syncthreads();
        float mfl[4];
        #pragma unroll
        for (int n = 0; n < 4; ++n)
            mfl[n] = (amask[b * SEQ + kv0 + n * 16 + fr] != 0) ? 1.f : 0.f;
        f32x4 s[2][4] = {};
        #pragma unroll
        for (int c = 0; c < 2; ++c) {
            bf16x8 kf[4];
            #pragma unroll
            for (int n = 0; n < 4; ++n) kf[n] = *(const bf16x8*)&Ks[(n * 16 + fr) * 72 + c * 32 + fg * 8];
            #pragma unroll
            for (int m = 0; m < 2; ++m)
                #pragma unroll
                for (int n = 0; n < 4; ++n)
                    s[m][n] = __builtin_amdgcn_mfma_f32_16x16x32_bf16(qf[m][c], kf[n], s[m][n], 0, 0, 0);
        }
        // scale + mask
        #pragma unroll
        for (int m = 0; m < 2; ++m)
            #pragma unroll
            for (int n = 0; n < 4; ++n)
                #pragma unroll
                for (int r = 0; r < 4; ++r) {
                    float sv = s[m][n][r] * 0.125f;
                    s[m][n][r] = (mfl[n] != 0.f) ? -100000.f : sv;
                }
        // online softmax
        #pragma unroll
        for (int m = 0; m < 2; ++m) {
            #pragma unroll
            for (int r = 0; r < 4; ++r) {
                float pm = fmaxf(fmaxf(s[m][0][r], s[m][1][r]), fmaxf(s[m][2][r], s[m][3][r]));
                pm = fmaxf(pm, __shfl_xor(pm, 1));
                pm = fmaxf(pm, __shfl_xor(pm, 2));
                pm = fmaxf(pm, __shfl_xor(pm, 4));
                pm = fmaxf(pm, __shfl_xor(pm, 8));
                float newm = fmaxf(mrun[m][r], pm);
                float corr = __expf(mrun[m][r] - newm);
                mrun[m][r] = newm;
                float ps = 0.f;
                #pragma unroll
                for (int n = 0; n < 4; ++n) {
                    float p = __expf(s[m][n][r] - newm);
                    s[m][n][r] = p;
                    ps += p;
                }
                ps += __shfl_xor(ps, 1);
                ps += __shfl_xor(ps, 2);
                ps += __shfl_xor(ps, 4);
                ps += __shfl_xor(ps, 8);
                lrun[m][r] = lrun[m][r] * corr + ps;
                #pragma unroll
                for (int dn = 0; dn < 4; ++dn) oacc[m][dn][r] *= corr;
            }
        }
        // P -> LDS (per-wave private region)
        #pragma unroll
        for (int m = 0; m < 2; ++m)
            #pragma unroll
            for (int n = 0; n < 4; ++n)
                #pragma unroll
                for (int r = 0; r < 4; ++r)
                    Ps[wid][(m * 16 + fg * 4 + r) * 72 + n * 16 + fr] = f2bf(s[m][n][r]);
        __syncthreads();
        // PV
        #pragma unroll
        for (int c = 0; c < 2; ++c) {
            bf16x8 pf[2], vf[4];
            #pragma unroll
            for (int m = 0; m < 2; ++m) pf[m] = *(const bf16x8*)&Ps[wid][(m * 16 + fr) * 72 + c * 32 + fg * 8];
            #pragma unroll
            for (int dn = 0; dn < 4; ++dn) vf[dn] = *(const bf16x8*)&Vts[(dn * 16 + fr) * 72 + c * 32 + fg * 8];
            #pragma unroll
            for (int m = 0; m < 2; ++m)
                #pragma unroll
                for (int dn = 0; dn < 4; ++dn)
                    oacc[m][dn] = __builtin_amdgcn_mfma_f32_16x16x32_bf16(pf[m], vf[dn], oacc[m][dn], 0, 0, 0);
        }
    }
    // epilogue with faithful-to-torch head scramble: i=b*16+h lands at b2=i&3, h2=i>>2
    const int b2 = bh & 3, h2 = bh >> 2;
    #pragma unroll
    for (int m = 0; m < 2; ++m)
        #pragma unroll
        for (int dn = 0; dn < 4; ++dn)
            #pragma unroll
            for (int r = 0; r < 4; ++r) {
                int q = q0 + m * 16 + fg * 4 + r;
                int d = dn * 16 + fr;
                float o = oacc[m][dn][r] / lrun[m][r];
                AF[((size_t)b2 * SEQ + q) * D_MODEL + h2 * DH + d] = f2bf(o);
            }
}

// ---------------- residual + LayerNorm ----------------
__global__ __launch_bounds__(256) void ln_kernel(const float* __restrict__ tmp,
                                                 const float* __restrict__ inp,
                                                 const float* __restrict__ g,
                                                 const float* __restrict__ bb,
                                                 float* __restrict__ out) {
    __shared__ float red[8];
    const int row = blockIdx.x, tid = threadIdx.x;
    float4 t = ((const float4*)(tmp + (size_t)row * D_MODEL))[tid];
    float4 rr = ((const float4*)(inp + (size_t)row * D_MODEL))[tid];
    float4 y;
    y.x = t.x + rr.x; y.y = t.y + rr.y; y.z = t.z + rr.z; y.w = t.w + rr.w;
    float sum = y.x + y.y + y.z + y.w;
    float sq = y.x * y.x + y.y * y.y + y.z * y.z + y.w * y.w;
    #pragma unroll
    for (int o = 1; o < 64; o <<= 1) { sum += __shfl_xor(sum, o); sq += __shfl_xor(sq, o); }
    int wid = tid >> 6, lane = tid & 63;
    if (lane == 0) { red[wid] = sum; red[4 + wid] = sq; }
    __syncthreads();
    sum = red[0] + red[1] + red[2] + red[3];
    sq = red[4] + red[5] + red[6] + red[7];
    float mu = sum * (1.f / D_MODEL);
    float var = sq * (1.f / D_MODEL) - mu * mu;
    float rs = rsqrtf(var + 1e-5f);
    float4 gg = ((const float4*)g)[tid];
    float4 bv = ((const float4*)bb)[tid];
    float4 o4;
    o4.x = (y.x - mu) * rs * gg.x + bv.x;
    o4.y = (y.y - mu) * rs * gg.y + bv.y;
    o4.z = (y.z - mu) * rs * gg.z + bv.z;
    o4.w = (y.w - mu) * rs * gg.w + bv.w;
    ((float4*)(out + (size_t)row * D_MODEL))[tid] = o4;
}

extern "C" void kernel_launch(void* const* d_in, const int* in_sizes, int n_in,
                              void* d_out, int out_size, void* d_ws, size_t ws_size,
                              hipStream_t stream) {
    const float* inp = (const float*)d_in[0];
    const int* amask = (const int*)d_in[1];
    const float* Wq = (const float*)d_in[2];
    const float* bq = (const float*)d_in[3];
    const float* Wk = (const float*)d_in[4];
    const float* bk = (const float*)d_in[5];
    const float* Wv = (const float*)d_in[6];
    const float* bv = (const float*)d_in[7];
    const float* Wo = (const float*)d_in[8];
    const float* lg = (const float*)d_in[9];
    const float* lb = (const float*)d_in[10];
    float* out = (float*)d_out;
    char* ws = (char*)d_ws;

    unsigned short* Xb     = (unsigned short*)(ws + 0);          //  8.0 MiB
    unsigned short* Wqkv_t = (unsigned short*)(ws + 8388608);    //  6.0 MiB
    unsigned short* Wo_t   = (unsigned short*)(ws + 14680064);   //  2.0 MiB
    unsigned short* Qb     = (unsigned short*)(ws + 16777216);   //  8.0 MiB
    unsigned short* Kb     = (unsigned short*)(ws + 25165824);   //  8.0 MiB
    unsigned short* Vb     = (unsigned short*)(ws + 33554432);   //  8.0 MiB
    unsigned short* AF     = (unsigned short*)(ws + 41943040);   //  8.0 MiB
    float*          tmp    = (float*)(ws + 50331648);            // 16.0 MiB  (total 64 MiB)

    cvt_x<<<4096, 256, 0, stream>>>(inp, Xb);
    transpose_w<<<dim3(32, 32, 4), dim3(32, 8), 0, stream>>>(Wq, Wk, Wv, Wo, Wqkv_t, Wo_t);
    gemm_qkv<<<dim3(32, 24), 256, 0, stream>>>(Xb, Wqkv_t, bq, bk, bv, Qb, Kb, Vb);
    attn_kernel<<<dim3(8, 64), 256, 0, stream>>>(Qb, Kb, Vb, amask, AF);
    gemm_o<<<dim3(32, 8), 256, 0, stream>>>(AF, Wo_t, tmp);
    ln_kernel<<<4096, 256, 0, stream>>>(tmp, inp, lg, lb, out);
}